// Round 8
// baseline (322.083 us; speedup 1.0000x reference)
//
#include <hip/hip_runtime.h>
#include <hip/hip_bf16.h>

// LiteMLA: B=8, C=256, H=W=64, N=HW=4096, td=256, d=8, heads=64
// ws: qkv bf16 (8,768,4096) | agg bf16 (8,768,4096) | att_f bf16 (8,64,4096,8)
//     | w_projbf bf16 (256,512) | kvb f32 (8,64,72)
// Pipeline: prep_w, qkv_gemm (MFMA), dw_agg (fused dw5x5+pw8x8, lane-linear LDS),
//           kv_pass, att_pass (-> att_f fragment layout), proj_gemm (LDS-free MFMA)

#define HW 4096
#define ATT_EPS 1e-15f
#define BN_EPS 1e-6f

typedef __attribute__((ext_vector_type(8))) short short8;
typedef __attribute__((ext_vector_type(4))) short short4v;
typedef __attribute__((ext_vector_type(4))) float f32x4;
typedef __attribute__((ext_vector_type(8))) unsigned short u16x8;
typedef __attribute__((ext_vector_type(4))) unsigned short u16x4;

static __device__ inline short f2bf(float f) {
    union { float f; unsigned u; } v; v.f = f;
    unsigned r = v.u + 0x7fff + ((v.u >> 16) & 1);   // RNE, finite inputs
    return (short)(r >> 16);
}
static __device__ inline float bf2f(unsigned short u) {
    union { unsigned u; float f; } v; v.u = (unsigned)u << 16; return v.f;
}

// ---------------- K0: w_proj f32 -> bf16 (256x512) ----------------
__global__ __launch_bounds__(256) void prep_w(const float* __restrict__ wproj,
                                              unsigned short* __restrict__ wbf) {
    const int i = (blockIdx.x * 256 + threadIdx.x) * 4;
    float4 v = *(const float4*)&wproj[i];
    u16x4 r = {(unsigned short)f2bf(v.x), (unsigned short)f2bf(v.y),
               (unsigned short)f2bf(v.z), (unsigned short)f2bf(v.w)};
    *(u16x4*)&wbf[i] = r;
}

// ---------------- K1: qkv(bf16) = W(768x256) @ X(256x4096), bf16 MFMA --------
__global__ __launch_bounds__(256) void qkv_gemm(const float* __restrict__ x,
                                                const float* __restrict__ w,
                                                unsigned short* __restrict__ qkv) {
    __shared__ short A_l[128 * 40];
    __shared__ short B_l[128 * 40];
    const int t  = threadIdx.x;
    const int b  = blockIdx.z;
    const int ob = blockIdx.y * 128;
    const int nb = blockIdx.x * 128;
    const float* xb = x + (size_t)b * 256 * HW;

    const int lane = t & 63, wave = t >> 6;
    const int wo = (wave >> 1) * 64, wn = (wave & 1) * 64;

    f32x4 acc[4][4];
#pragma unroll
    for (int s = 0; s < 4; s++)
#pragma unroll
        for (int u = 0; u < 4; u++) acc[s][u] = (f32x4){0.f, 0.f, 0.f, 0.f};

    const int col4 = (t & 7) * 4;
    const int r0   = t >> 3;            // 0..31
    for (int kb = 0; kb < 256; kb += 32) {
        __syncthreads();
#pragma unroll
        for (int i = 0; i < 4; i++) {
            const int r = r0 + 32 * i;
            float4 v = *(const float4*)&w[(ob + r) * 256 + kb + col4];
            short4v s4 = {f2bf(v.x), f2bf(v.y), f2bf(v.z), f2bf(v.w)};
            *(short4v*)&A_l[r * 40 + col4] = s4;
        }
#pragma unroll
        for (int i = 0; i < 4; i++) {
            const int n4 = (t & 7) + 8 * i;
            float4 v = *(const float4*)&xb[(size_t)(kb + r0) * HW + nb + n4 * 4];
            B_l[(n4 * 4 + 0) * 40 + r0] = f2bf(v.x);
            B_l[(n4 * 4 + 1) * 40 + r0] = f2bf(v.y);
            B_l[(n4 * 4 + 2) * 40 + r0] = f2bf(v.z);
            B_l[(n4 * 4 + 3) * 40 + r0] = f2bf(v.w);
        }
        __syncthreads();

        short8 af[4], bf[4];
#pragma unroll
        for (int s = 0; s < 4; s++)
            af[s] = *(const short8*)&A_l[(wo + s * 16 + (lane & 15)) * 40 + (lane >> 4) * 8];
#pragma unroll
        for (int u = 0; u < 4; u++)
            bf[u] = *(const short8*)&B_l[(wn + u * 16 + (lane & 15)) * 40 + (lane >> 4) * 8];
#pragma unroll
        for (int s = 0; s < 4; s++)
#pragma unroll
            for (int u = 0; u < 4; u++)
                acc[s][u] = __builtin_amdgcn_mfma_f32_16x16x32_bf16(af[s], bf[u], acc[s][u], 0, 0, 0);
    }

#pragma unroll
    for (int s = 0; s < 4; s++)
#pragma unroll
        for (int u = 0; u < 4; u++)
#pragma unroll
            for (int r = 0; r < 4; r++) {
                const int o = ob + wo + s * 16 + (lane >> 4) * 4 + r;
                const int n = nb + wn + u * 16 + (lane & 15);
                qkv[((size_t)b * 768 + o) * HW + n] = (unsigned short)f2bf(acc[s][u][r]);
            }
}

// ---------------- K2: fused dw5x5 + pw8x8, lane-linear bf16 LDS tile ---------
// grid (4 ytiles(16 rows), 96 g, 8 b), block 256. Thread: 1 row x 4 col x 8 ch.
// Tile: u16 [8ch][20r][64c] flat (row stride 64 => wave addr = const + lane*4
// shorts => all LDS accesses lane-linear, conflict-free). x-halo via neighbor
// octet reads + tx-edge masking; 8-short guards keep edge addrs legal.
__global__ __launch_bounds__(256) void dw_agg(const unsigned short* __restrict__ qkv,
                                              const float* __restrict__ wdw,
                                              const float* __restrict__ wpw,
                                              unsigned short* __restrict__ agg) {
    __shared__ unsigned short tile_raw[8 + 8 * 20 * 64 + 8];   // ~41 KB? no: 20496*2B = 41 KB... (bf16) 40.0 KB
    __shared__ float wk[8][25];
    __shared__ float pw[64];
    unsigned short* base = tile_raw + 8;
    const int b = blockIdx.z, g = blockIdx.y;
    const int y0 = blockIdx.x * 16;
    const int t = threadIdx.x;

    if (t < 200) wk[t / 25][t % 25] = wdw[(g * 8) * 25 + t];
    if (t < 64)  pw[t] = wpw[g * 64 + t];

    // zero + fill: slot i handled by thread i%256 in both loops -> no race.
    // i over 8ch x 20r x 8 col-octets = 1280 u16x8 slots, lane-linear.
#pragma unroll
    for (int k = 0; k < 5; k++) {
        const int i = t + 256 * k;
        const int c8 = i & 7, rr = (i >> 3) % 20, ch = i / 160;
        const int y = y0 - 2 + rr;
        u16x8 v = {0, 0, 0, 0, 0, 0, 0, 0};
        if (y >= 0 && y < 64)
            v = *(const u16x8*)&qkv[((size_t)(b * 768 + g * 8 + ch)) * HW + y * 64 + c8 * 8];
        *(u16x8*)&base[i * 8] = v;
    }
    __syncthreads();

    const int tx = t & 15, ty = t >> 4;     // col-quad, output row
    float dwres[8][4];
#pragma unroll
    for (int ch = 0; ch < 8; ch++) {
        float a0 = 0.f, a1 = 0.f, a2 = 0.f, a3 = 0.f;
#pragma unroll
        for (int dy = 0; dy < 5; dy++) {
            const int off = ch * 1280 + (ty + dy) * 64 + tx * 4;
            u16x4 L  = *(const u16x4*)&base[off - 4];
            u16x4 C  = *(const u16x4*)&base[off];
            u16x4 R  = *(const u16x4*)&base[off + 4];
            float win[8];
            win[0] = (tx == 0)  ? 0.f : bf2f(L[2]);
            win[1] = (tx == 0)  ? 0.f : bf2f(L[3]);
            win[2] = bf2f(C[0]); win[3] = bf2f(C[1]);
            win[4] = bf2f(C[2]); win[5] = bf2f(C[3]);
            win[6] = (tx == 15) ? 0.f : bf2f(R[0]);
            win[7] = (tx == 15) ? 0.f : bf2f(R[1]);
#pragma unroll
            for (int dx = 0; dx < 5; dx++) {
                const float wv = wk[ch][dy * 5 + dx];
                a0 += wv * win[dx + 0];
                a1 += wv * win[dx + 1];
                a2 += wv * win[dx + 2];
                a3 += wv * win[dx + 3];
            }
        }
        dwres[ch][0] = a0; dwres[ch][1] = a1; dwres[ch][2] = a2; dwres[ch][3] = a3;
    }
#pragma unroll
    for (int o = 0; o < 8; o++) {
        float s0 = 0.f, s1 = 0.f, s2 = 0.f, s3 = 0.f;
#pragma unroll
        for (int i = 0; i < 8; i++) {
            const float wv = pw[o * 8 + i];
            s0 += wv * dwres[i][0]; s1 += wv * dwres[i][1];
            s2 += wv * dwres[i][2]; s3 += wv * dwres[i][3];
        }
        u16x4 rv = {(unsigned short)f2bf(s0), (unsigned short)f2bf(s1),
                    (unsigned short)f2bf(s2), (unsigned short)f2bf(s3)};
        *(u16x4*)&agg[((size_t)(b * 768 + g * 8 + o)) * HW + (y0 + ty) * 64 + tx * 4] = rv;
    }
}

// ---------------- K3: kv[d][e] = sum_n relu(k[n,d]) * vpad[n,e], bf16 in -----
__global__ __launch_bounds__(256) void kv_pass(const unsigned short* __restrict__ qkv,
                                               const unsigned short* __restrict__ agg,
                                               float* __restrict__ kvout) {
    const int h = blockIdx.x, b = blockIdx.y;
    const unsigned short* buf = (h < 32) ? qkv : agg;
    const int cbase = (h < 32) ? h * 24 : (h - 32) * 24;
    const u16x4* kp4 = (const u16x4*)(buf + ((size_t)b * 768 + cbase + 8)  * HW);
    const u16x4* vp4 = (const u16x4*)(buf + ((size_t)b * 768 + cbase + 16) * HW);

    float acc[8][9];
#pragma unroll
    for (int d = 0; d < 8; d++)
#pragma unroll
        for (int e = 0; e < 9; e++) acc[d][e] = 0.f;

#pragma unroll
    for (int k = 0; k < 4; k++) {
        const int nn = threadIdx.x + k * 256;
        float kk[8][4];
#pragma unroll
        for (int d = 0; d < 8; d++) {
            u16x4 v = kp4[d * 1024 + nn];
            kk[d][0] = fmaxf(bf2f(v.x), 0.f); kk[d][1] = fmaxf(bf2f(v.y), 0.f);
            kk[d][2] = fmaxf(bf2f(v.z), 0.f); kk[d][3] = fmaxf(bf2f(v.w), 0.f);
        }
#pragma unroll
        for (int e = 0; e < 8; e++) {
            u16x4 vr = vp4[e * 1024 + nn];
            float v0 = bf2f(vr.x), v1 = bf2f(vr.y), v2 = bf2f(vr.z), v3 = bf2f(vr.w);
#pragma unroll
            for (int d = 0; d < 8; d++)
                acc[d][e] += kk[d][0] * v0 + kk[d][1] * v1 + kk[d][2] * v2 + kk[d][3] * v3;
        }
#pragma unroll
        for (int d = 0; d < 8; d++)
            acc[d][8] += kk[d][0] + kk[d][1] + kk[d][2] + kk[d][3];
    }

    __shared__ float red[4][72];
    const int lane = threadIdx.x & 63, wv = threadIdx.x >> 6;
#pragma unroll
    for (int d = 0; d < 8; d++) {
#pragma unroll
        for (int e = 0; e < 9; e++) {
            float v = acc[d][e];
            v += __shfl_xor(v, 1);  v += __shfl_xor(v, 2);
            v += __shfl_xor(v, 4);  v += __shfl_xor(v, 8);
            v += __shfl_xor(v, 16); v += __shfl_xor(v, 32);
            if (lane == 0) red[wv][d * 9 + e] = v;
        }
    }
    __syncthreads();
    if (threadIdx.x < 72) {
        float s = red[0][threadIdx.x] + red[1][threadIdx.x] +
                  red[2][threadIdx.x] + red[3][threadIdx.x];
        kvout[((size_t)(b * 64 + h)) * 72 + threadIdx.x] = s;
    }
}

// ---------------- K4: att -> att_f[b][h][n][8] (B-fragment-ready bf16) -------
__global__ __launch_bounds__(256) void att_pass(const unsigned short* __restrict__ qkv,
                                                const unsigned short* __restrict__ agg,
                                                const float* __restrict__ kvbuf,
                                                unsigned short* __restrict__ att_f) {
    __shared__ float kvl[72];
    const int h = blockIdx.y, b = blockIdx.z;
    const int t = threadIdx.x;
    if (t < 72) kvl[t] = kvbuf[((size_t)(b * 64 + h)) * 72 + t];
    __syncthreads();

    const unsigned short* buf = (h < 32) ? qkv : agg;
    const int cbase = (h & 31) * 24;
    const int n0 = (blockIdx.x * 256 + t) * 8;
    const unsigned short* qp = buf + ((size_t)b * 768 + cbase) * HW + n0;

    float q[8][8];
#pragma unroll
    for (int d = 0; d < 8; d++) {
        u16x8 v = *(const u16x8*)&qp[(size_t)d * HW];
#pragma unroll
        for (int j = 0; j < 8; j++) q[d][j] = fmaxf(bf2f(v[j]), 0.f);
    }

    unsigned short* op = att_f + (((size_t)(b * 64 + h)) * HW + n0) * 8;
#pragma unroll
    for (int j = 0; j < 8; j++) {
        float num[9];
#pragma unroll
        for (int e = 0; e < 9; e++) num[e] = 0.f;
#pragma unroll
        for (int d = 0; d < 8; d++) {
            const float qv = q[d][j];
            const float* kvh = &kvl[d * 9];
#pragma unroll
            for (int e = 0; e < 9; e++) num[e] += qv * kvh[e];
        }
        const float rden = 1.f / (num[8] + ATT_EPS);
        u16x8 r;
#pragma unroll
        for (int e = 0; e < 8; e++) r[e] = (unsigned short)f2bf(num[e] * rden);
        *(u16x8*)&op[j * 8] = r;
    }
}

// ---------------- K5: p = Wp @ att, BN, +x — LDS-free direct-frag MFMA -------
__global__ __launch_bounds__(256) void proj_gemm(const unsigned short* __restrict__ wbf,
                                                 const unsigned short* __restrict__ att_f,
                                                 const float* __restrict__ gamma,
                                                 const float* __restrict__ beta,
                                                 const float* __restrict__ mean,
                                                 const float* __restrict__ var,
                                                 const float* __restrict__ x,
                                                 float* __restrict__ out) {
    const int t  = threadIdx.x;
    const int b  = blockIdx.z;
    const int ob = blockIdx.y * 128;
    const int nb = blockIdx.x * 128;
    const int lane = t & 63, wave = t >> 6;
    const int wo = (wave >> 1) * 64, wn = (wave & 1) * 64;

    const int am = lane & 15, ak = lane >> 4;
    const unsigned short* ap0 = wbf + (size_t)(ob + wo + am) * 512 + ak * 8;
    const unsigned short* bp0 = att_f +
        (((size_t)b * 64 + ak) * HW + nb + wn + am) * 8;

    f32x4 acc[4][4];
#pragma unroll
    for (int s = 0; s < 4; s++)
#pragma unroll
        for (int u = 0; u < 4; u++) acc[s][u] = (f32x4){0.f, 0.f, 0.f, 0.f};

    for (int kb = 0; kb < 512; kb += 32) {
        short8 af[4], bf[4];
#pragma unroll
        for (int s = 0; s < 4; s++)
            af[s] = *(const short8*)(ap0 + (size_t)s * 16 * 512 + kb);
#pragma unroll
        for (int u = 0; u < 4; u++)
            bf[u] = *(const short8*)(bp0 + ((size_t)(kb >> 3) * HW + u * 16) * 8);
#pragma unroll
        for (int s = 0; s < 4; s++)
#pragma unroll
            for (int u = 0; u < 4; u++)
                acc[s][u] = __builtin_amdgcn_mfma_f32_16x16x32_bf16(af[s], bf[u], acc[s][u], 0, 0, 0);
    }

#pragma unroll
    for (int s = 0; s < 4; s++) {
        const int o_base = ob + wo + s * 16 + (lane >> 4) * 4;
#pragma unroll
        for (int r = 0; r < 4; r++) {
            const int o = o_base + r;
            const float inv = gamma[o] * rsqrtf(var[o] + BN_EPS);
            const float sh  = beta[o] - mean[o] * inv;
#pragma unroll
            for (int u = 0; u < 4; u++) {
                const int n = nb + wn + u * 16 + (lane & 15);
                const size_t idx = ((size_t)b * 256 + o) * HW + n;
                out[idx] = x[idx] + acc[s][u][r] * inv + sh;
            }
        }
    }
}

extern "C" void kernel_launch(void* const* d_in, const int* in_sizes, int n_in,
                              void* d_out, int out_size, void* d_ws, size_t ws_size,
                              hipStream_t stream) {
    const float* x      = (const float*)d_in[0];
    const float* w_qkv  = (const float*)d_in[1];
    const float* w_dw   = (const float*)d_in[2];
    const float* w_pw   = (const float*)d_in[3];
    const float* w_proj = (const float*)d_in[4];
    const float* gamma  = (const float*)d_in[5];
    const float* beta   = (const float*)d_in[6];
    const float* mean   = (const float*)d_in[7];
    const float* var    = (const float*)d_in[8];
    float* out = (float*)d_out;

    unsigned short* qkv  = (unsigned short*)d_ws;      // 25165824 shorts
    unsigned short* agg  = qkv + (size_t)25165824;     // 25165824 shorts
    unsigned short* attf = agg + (size_t)25165824;     // 16777216 shorts
    unsigned short* wbf  = attf + (size_t)16777216;    // 131072 shorts
    float* kvb = (float*)(wbf + (size_t)131072);       // 36864 floats

    prep_w  <<<dim3(128),       256, 0, stream>>>(w_proj, wbf);
    qkv_gemm<<<dim3(32, 6, 8),  256, 0, stream>>>(x, w_qkv, qkv);
    dw_agg  <<<dim3(4, 96, 8),  256, 0, stream>>>(qkv, w_dw, w_pw, agg);
    kv_pass <<<dim3(64, 8),     256, 0, stream>>>(qkv, agg, kvb);
    att_pass<<<dim3(2, 64, 8),  256, 0, stream>>>(qkv, agg, kvb, attf);
    proj_gemm<<<dim3(32, 2, 8), 256, 0, stream>>>(wbf, attf,
                                                  gamma, beta, mean, var, x, out);
}

// Round 9
// 253.901 us; speedup vs baseline: 1.2685x; 1.2685x over previous
//
#include <hip/hip_runtime.h>
#include <hip/hip_bf16.h>

// LiteMLA: B=8, C=256, H=W=64, N=HW=4096, td=256, d=8, heads=64
// ws: qkv bf16 (8,768,4096) | agg bf16 (8,768,4096) | att_f bf16 (8,64,4096,8)
//     | w_projbf bf16 (256,512) | kvb f32 (8,64,72)
// Pipeline: prep_w, qkv_gemm (MFMA), dw_agg (fused dw5x5+pw8x8, lane-linear LDS),
//           kv_pass, att_pass (-> att_f fragment layout), proj_gemm (LDS-free MFMA)

#define HW 4096
#define ATT_EPS 1e-15f
#define BN_EPS 1e-6f

typedef __attribute__((ext_vector_type(8))) short short8;
typedef __attribute__((ext_vector_type(4))) short short4v;
typedef __attribute__((ext_vector_type(4))) float f32x4;
typedef __attribute__((ext_vector_type(8))) unsigned short u16x8;
typedef __attribute__((ext_vector_type(4))) unsigned short u16x4;

static __device__ inline short f2bf(float f) {
    union { float f; unsigned u; } v; v.f = f;
    unsigned r = v.u + 0x7fff + ((v.u >> 16) & 1);   // RNE, finite inputs
    return (short)(r >> 16);
}
static __device__ inline float bf2f(unsigned short u) {
    union { unsigned u; float f; } v; v.u = (unsigned)u << 16; return v.f;
}

// ---------------- K0: w_proj f32 -> bf16 (256x512) ----------------
__global__ __launch_bounds__(256) void prep_w(const float* __restrict__ wproj,
                                              unsigned short* __restrict__ wbf) {
    const int i = (blockIdx.x * 256 + threadIdx.x) * 4;
    float4 v = *(const float4*)&wproj[i];
    u16x4 r = {(unsigned short)f2bf(v.x), (unsigned short)f2bf(v.y),
               (unsigned short)f2bf(v.z), (unsigned short)f2bf(v.w)};
    *(u16x4*)&wbf[i] = r;
}

// ---------------- K1: qkv(bf16) = W(768x256) @ X(256x4096), bf16 MFMA --------
__global__ __launch_bounds__(256) void qkv_gemm(const float* __restrict__ x,
                                                const float* __restrict__ w,
                                                unsigned short* __restrict__ qkv) {
    __shared__ short A_l[128 * 40];
    __shared__ short B_l[128 * 40];
    const int t  = threadIdx.x;
    const int b  = blockIdx.z;
    const int ob = blockIdx.y * 128;
    const int nb = blockIdx.x * 128;
    const float* xb = x + (size_t)b * 256 * HW;

    const int lane = t & 63, wave = t >> 6;
    const int wo = (wave >> 1) * 64, wn = (wave & 1) * 64;

    f32x4 acc[4][4];
#pragma unroll
    for (int s = 0; s < 4; s++)
#pragma unroll
        for (int u = 0; u < 4; u++) acc[s][u] = (f32x4){0.f, 0.f, 0.f, 0.f};

    const int col4 = (t & 7) * 4;
    const int r0   = t >> 3;            // 0..31
    for (int kb = 0; kb < 256; kb += 32) {
        __syncthreads();
#pragma unroll
        for (int i = 0; i < 4; i++) {
            const int r = r0 + 32 * i;
            float4 v = *(const float4*)&w[(ob + r) * 256 + kb + col4];
            short4v s4 = {f2bf(v.x), f2bf(v.y), f2bf(v.z), f2bf(v.w)};
            *(short4v*)&A_l[r * 40 + col4] = s4;
        }
#pragma unroll
        for (int i = 0; i < 4; i++) {
            const int n4 = (t & 7) + 8 * i;
            float4 v = *(const float4*)&xb[(size_t)(kb + r0) * HW + nb + n4 * 4];
            B_l[(n4 * 4 + 0) * 40 + r0] = f2bf(v.x);
            B_l[(n4 * 4 + 1) * 40 + r0] = f2bf(v.y);
            B_l[(n4 * 4 + 2) * 40 + r0] = f2bf(v.z);
            B_l[(n4 * 4 + 3) * 40 + r0] = f2bf(v.w);
        }
        __syncthreads();

        short8 af[4], bf[4];
#pragma unroll
        for (int s = 0; s < 4; s++)
            af[s] = *(const short8*)&A_l[(wo + s * 16 + (lane & 15)) * 40 + (lane >> 4) * 8];
#pragma unroll
        for (int u = 0; u < 4; u++)
            bf[u] = *(const short8*)&B_l[(wn + u * 16 + (lane & 15)) * 40 + (lane >> 4) * 8];
#pragma unroll
        for (int s = 0; s < 4; s++)
#pragma unroll
            for (int u = 0; u < 4; u++)
                acc[s][u] = __builtin_amdgcn_mfma_f32_16x16x32_bf16(af[s], bf[u], acc[s][u], 0, 0, 0);
    }

#pragma unroll
    for (int s = 0; s < 4; s++)
#pragma unroll
        for (int u = 0; u < 4; u++)
#pragma unroll
            for (int r = 0; r < 4; r++) {
                const int o = ob + wo + s * 16 + (lane >> 4) * 4 + r;
                const int n = nb + wn + u * 16 + (lane & 15);
                qkv[((size_t)b * 768 + o) * HW + n] = (unsigned short)f2bf(acc[s][u][r]);
            }
}

// ---------------- K2: fused dw5x5 + pw8x8, lane-linear bf16 LDS tile ---------
// grid (4 ytiles(16 rows), 96 g, 8 b), block 256. Thread: 1 row x 4 col x 8 ch.
// Tile u16 [8ch][20r][64c] flat: all LDS access lane-linear (4-way worst case,
// measured ~0.7 cyc/read extra). ch loop NOT unrolled + pw folded per-ch +
// launch_bounds(256,5): keeps VGPR ~<=102 (R8 regression: 256 VGPR, 11% occ).
__global__ __launch_bounds__(256, 5) void dw_agg(const unsigned short* __restrict__ qkv,
                                                 const float* __restrict__ wdw,
                                                 const float* __restrict__ wpw,
                                                 unsigned short* __restrict__ agg) {
    __shared__ unsigned short tile_raw[8 + 8 * 20 * 64 + 8];   // 20.1 KB
    __shared__ float wk[8][25];
    __shared__ float pw[64];
    unsigned short* base = tile_raw + 8;
    const int b = blockIdx.z, g = blockIdx.y;
    const int y0 = blockIdx.x * 16;
    const int t = threadIdx.x;

    if (t < 200) wk[t / 25][t % 25] = wdw[(g * 8) * 25 + t];
    if (t < 64)  pw[t] = wpw[g * 64 + t];

    // fill: 1280 u16x8 slots (8ch x 20r x 8 col-octets), lane-linear writes.
#pragma unroll
    for (int k = 0; k < 5; k++) {
        const int i = t + 256 * k;
        const int c8 = i & 7, rr = (i >> 3) % 20, ch = i / 160;
        const int y = y0 - 2 + rr;
        u16x8 v = {0, 0, 0, 0, 0, 0, 0, 0};
        if (y >= 0 && y < 64)
            v = *(const u16x8*)&qkv[((size_t)(b * 768 + g * 8 + ch)) * HW + y * 64 + c8 * 8];
        *(u16x8*)&base[i * 8] = v;
    }
    __syncthreads();

    const int tx = t & 15, ty = t >> 4;     // col-quad, output row
    float out[8][4];
#pragma unroll
    for (int o = 0; o < 8; o++)
#pragma unroll
        for (int j = 0; j < 4; j++) out[o][j] = 0.f;

#pragma unroll 1
    for (int ch = 0; ch < 8; ch++) {
        float a0 = 0.f, a1 = 0.f, a2 = 0.f, a3 = 0.f;
#pragma unroll
        for (int dy = 0; dy < 5; dy++) {
            const int off = ch * 1280 + (ty + dy) * 64 + tx * 4;
            u16x4 L  = *(const u16x4*)&base[off - 4];
            u16x4 C  = *(const u16x4*)&base[off];
            u16x4 R  = *(const u16x4*)&base[off + 4];
            float win[8];
            win[0] = (tx == 0)  ? 0.f : bf2f(L[2]);
            win[1] = (tx == 0)  ? 0.f : bf2f(L[3]);
            win[2] = bf2f(C[0]); win[3] = bf2f(C[1]);
            win[4] = bf2f(C[2]); win[5] = bf2f(C[3]);
            win[6] = (tx == 15) ? 0.f : bf2f(R[0]);
            win[7] = (tx == 15) ? 0.f : bf2f(R[1]);
#pragma unroll
            for (int dx = 0; dx < 5; dx++) {
                const float wv = wk[ch][dy * 5 + dx];
                a0 += wv * win[dx + 0];
                a1 += wv * win[dx + 1];
                a2 += wv * win[dx + 2];
                a3 += wv * win[dx + 3];
            }
        }
#pragma unroll
        for (int o = 0; o < 8; o++) {
            const float wv = pw[o * 8 + ch];
            out[o][0] += wv * a0; out[o][1] += wv * a1;
            out[o][2] += wv * a2; out[o][3] += wv * a3;
        }
    }

#pragma unroll
    for (int o = 0; o < 8; o++) {
        u16x4 rv = {(unsigned short)f2bf(out[o][0]), (unsigned short)f2bf(out[o][1]),
                    (unsigned short)f2bf(out[o][2]), (unsigned short)f2bf(out[o][3])};
        *(u16x4*)&agg[((size_t)(b * 768 + g * 8 + o)) * HW + (y0 + ty) * 64 + tx * 4] = rv;
    }
}

// ---------------- K3: kv[d][e] = sum_n relu(k[n,d]) * vpad[n,e], bf16 in -----
__global__ __launch_bounds__(256) void kv_pass(const unsigned short* __restrict__ qkv,
                                               const unsigned short* __restrict__ agg,
                                               float* __restrict__ kvout) {
    const int h = blockIdx.x, b = blockIdx.y;
    const unsigned short* buf = (h < 32) ? qkv : agg;
    const int cbase = (h < 32) ? h * 24 : (h - 32) * 24;
    const u16x4* kp4 = (const u16x4*)(buf + ((size_t)b * 768 + cbase + 8)  * HW);
    const u16x4* vp4 = (const u16x4*)(buf + ((size_t)b * 768 + cbase + 16) * HW);

    float acc[8][9];
#pragma unroll
    for (int d = 0; d < 8; d++)
#pragma unroll
        for (int e = 0; e < 9; e++) acc[d][e] = 0.f;

#pragma unroll
    for (int k = 0; k < 4; k++) {
        const int nn = threadIdx.x + k * 256;
        float kk[8][4];
#pragma unroll
        for (int d = 0; d < 8; d++) {
            u16x4 v = kp4[d * 1024 + nn];
            kk[d][0] = fmaxf(bf2f(v.x), 0.f); kk[d][1] = fmaxf(bf2f(v.y), 0.f);
            kk[d][2] = fmaxf(bf2f(v.z), 0.f); kk[d][3] = fmaxf(bf2f(v.w), 0.f);
        }
#pragma unroll
        for (int e = 0; e < 8; e++) {
            u16x4 vr = vp4[e * 1024 + nn];
            float v0 = bf2f(vr.x), v1 = bf2f(vr.y), v2 = bf2f(vr.z), v3 = bf2f(vr.w);
#pragma unroll
            for (int d = 0; d < 8; d++)
                acc[d][e] += kk[d][0] * v0 + kk[d][1] * v1 + kk[d][2] * v2 + kk[d][3] * v3;
        }
#pragma unroll
        for (int d = 0; d < 8; d++)
            acc[d][8] += kk[d][0] + kk[d][1] + kk[d][2] + kk[d][3];
    }

    __shared__ float red[4][72];
    const int lane = threadIdx.x & 63, wv = threadIdx.x >> 6;
#pragma unroll
    for (int d = 0; d < 8; d++) {
#pragma unroll
        for (int e = 0; e < 9; e++) {
            float v = acc[d][e];
            v += __shfl_xor(v, 1);  v += __shfl_xor(v, 2);
            v += __shfl_xor(v, 4);  v += __shfl_xor(v, 8);
            v += __shfl_xor(v, 16); v += __shfl_xor(v, 32);
            if (lane == 0) red[wv][d * 9 + e] = v;
        }
    }
    __syncthreads();
    if (threadIdx.x < 72) {
        float s = red[0][threadIdx.x] + red[1][threadIdx.x] +
                  red[2][threadIdx.x] + red[3][threadIdx.x];
        kvout[((size_t)(b * 64 + h)) * 72 + threadIdx.x] = s;
    }
}

// ---------------- K4: att -> att_f[b][h][n][8] (B-fragment-ready bf16) -------
__global__ __launch_bounds__(256) void att_pass(const unsigned short* __restrict__ qkv,
                                                const unsigned short* __restrict__ agg,
                                                const float* __restrict__ kvbuf,
                                                unsigned short* __restrict__ att_f) {
    __shared__ float kvl[72];
    const int h = blockIdx.y, b = blockIdx.z;
    const int t = threadIdx.x;
    if (t < 72) kvl[t] = kvbuf[((size_t)(b * 64 + h)) * 72 + t];
    __syncthreads();

    const unsigned short* buf = (h < 32) ? qkv : agg;
    const int cbase = (h & 31) * 24;
    const int n0 = (blockIdx.x * 256 + t) * 8;
    const unsigned short* qp = buf + ((size_t)b * 768 + cbase) * HW + n0;

    float q[8][8];
#pragma unroll
    for (int d = 0; d < 8; d++) {
        u16x8 v = *(const u16x8*)&qp[(size_t)d * HW];
#pragma unroll
        for (int j = 0; j < 8; j++) q[d][j] = fmaxf(bf2f(v[j]), 0.f);
    }

    unsigned short* op = att_f + (((size_t)(b * 64 + h)) * HW + n0) * 8;
#pragma unroll
    for (int j = 0; j < 8; j++) {
        float num[9];
#pragma unroll
        for (int e = 0; e < 9; e++) num[e] = 0.f;
#pragma unroll
        for (int d = 0; d < 8; d++) {
            const float qv = q[d][j];
            const float* kvh = &kvl[d * 9];
#pragma unroll
            for (int e = 0; e < 9; e++) num[e] += qv * kvh[e];
        }
        const float rden = 1.f / (num[8] + ATT_EPS);
        u16x8 r;
#pragma unroll
        for (int e = 0; e < 8; e++) r[e] = (unsigned short)f2bf(num[e] * rden);
        *(u16x8*)&op[j * 8] = r;
    }
}

// ---------------- K5: p = Wp @ att, BN, +x — LDS-free direct-frag MFMA -------
__global__ __launch_bounds__(256) void proj_gemm(const unsigned short* __restrict__ wbf,
                                                 const unsigned short* __restrict__ att_f,
                                                 const float* __restrict__ gamma,
                                                 const float* __restrict__ beta,
                                                 const float* __restrict__ mean,
                                                 const float* __restrict__ var,
                                                 const float* __restrict__ x,
                                                 float* __restrict__ out) {
    const int t  = threadIdx.x;
    const int b  = blockIdx.z;
    const int ob = blockIdx.y * 128;
    const int nb = blockIdx.x * 128;
    const int lane = t & 63, wave = t >> 6;
    const int wo = (wave >> 1) * 64, wn = (wave & 1) * 64;

    const int am = lane & 15, ak = lane >> 4;
    const unsigned short* ap0 = wbf + (size_t)(ob + wo + am) * 512 + ak * 8;
    const unsigned short* bp0 = att_f +
        (((size_t)b * 64 + ak) * HW + nb + wn + am) * 8;

    f32x4 acc[4][4];
#pragma unroll
    for (int s = 0; s < 4; s++)
#pragma unroll
        for (int u = 0; u < 4; u++) acc[s][u] = (f32x4){0.f, 0.f, 0.f, 0.f};

    for (int kb = 0; kb < 512; kb += 32) {
        short8 af[4], bf[4];
#pragma unroll
        for (int s = 0; s < 4; s++)
            af[s] = *(const short8*)(ap0 + (size_t)s * 16 * 512 + kb);
#pragma unroll
        for (int u = 0; u < 4; u++)
            bf[u] = *(const short8*)(bp0 + ((size_t)(kb >> 3) * HW + u * 16) * 8);
#pragma unroll
        for (int s = 0; s < 4; s++)
#pragma unroll
            for (int u = 0; u < 4; u++)
                acc[s][u] = __builtin_amdgcn_mfma_f32_16x16x32_bf16(af[s], bf[u], acc[s][u], 0, 0, 0);
    }

#pragma unroll
    for (int s = 0; s < 4; s++) {
        const int o_base = ob + wo + s * 16 + (lane >> 4) * 4;
#pragma unroll
        for (int r = 0; r < 4; r++) {
            const int o = o_base + r;
            const float inv = gamma[o] * rsqrtf(var[o] + BN_EPS);
            const float sh  = beta[o] - mean[o] * inv;
#pragma unroll
            for (int u = 0; u < 4; u++) {
                const int n = nb + wn + u * 16 + (lane & 15);
                const size_t idx = ((size_t)b * 256 + o) * HW + n;
                out[idx] = x[idx] + acc[s][u][r] * inv + sh;
            }
        }
    }
}

extern "C" void kernel_launch(void* const* d_in, const int* in_sizes, int n_in,
                              void* d_out, int out_size, void* d_ws, size_t ws_size,
                              hipStream_t stream) {
    const float* x      = (const float*)d_in[0];
    const float* w_qkv  = (const float*)d_in[1];
    const float* w_dw   = (const float*)d_in[2];
    const float* w_pw   = (const float*)d_in[3];
    const float* w_proj = (const float*)d_in[4];
    const float* gamma  = (const float*)d_in[5];
    const float* beta   = (const float*)d_in[6];
    const float* mean   = (const float*)d_in[7];
    const float* var    = (const float*)d_in[8];
    float* out = (float*)d_out;

    unsigned short* qkv  = (unsigned short*)d_ws;      // 25165824 shorts
    unsigned short* agg  = qkv + (size_t)25165824;     // 25165824 shorts
    unsigned short* attf = agg + (size_t)25165824;     // 16777216 shorts
    unsigned short* wbf  = attf + (size_t)16777216;    // 131072 shorts
    float* kvb = (float*)(wbf + (size_t)131072);       // 36864 floats

    prep_w  <<<dim3(128),       256, 0, stream>>>(w_proj, wbf);
    qkv_gemm<<<dim3(32, 6, 8),  256, 0, stream>>>(x, w_qkv, qkv);
    dw_agg  <<<dim3(4, 96, 8),  256, 0, stream>>>(qkv, w_dw, w_pw, agg);
    kv_pass <<<dim3(64, 8),     256, 0, stream>>>(qkv, agg, kvb);
    att_pass<<<dim3(2, 64, 8),  256, 0, stream>>>(qkv, agg, kvb, attf);
    proj_gemm<<<dim3(32, 2, 8), 256, 0, stream>>>(wbf, attf,
                                                  gamma, beta, mean, var, x, out);
}